// Round 19
// baseline (4359.798 us; speedup 1.0000x reference)
//
#include <hip/hip_runtime.h>
#include <math.h>

#define N_PTS 262144
#define KC 256
#define DIM 64
#define MAX_ITERS 10

// ===========================================================================
// Bit-exact XLA:CPU f32 arithmetic (validated R11-R18 — DO NOT ALTER):
//   x2/c2: rounded squares (fmaf(v,v,0)) + strict sequential f32 add chain
//   dot:   ascending-k FMA chain;  d2 = (x2 + c2) - 2*dot
//   argmin: strict-< first-min, first-NaN override
//   segment_sum: per (k,d), i-ascending sequential plain f32 adds
//   update: f32 sums/counts division (0/0 -> NaN)
// R19: role-separated LDS double-buffer for the chain. R16's version made
// wave 0 stage too (slot = t + i2*256 included t<64), serializing gather
// latency into the chain wave. Now waves 1-3 stage chunk c+1 while wave 0
// ONLY reads LDS and chains chunk c. Consumer never issues a global load.
// ===========================================================================

__device__ __forceinline__ float seq_rowsum_sq64(const float* p)
{
    float s = fmaf(p[0], p[0], 0.f);
    #pragma unroll
    for (int d = 1; d < DIM; ++d) s = s + fmaf(p[d], p[d], 0.f);
    return s;
}

__global__ void detect_idx(const int* __restrict__ a, int* __restrict__ mode)
{
    int zeros = 0;
    for (int j = 1; j < 256; j += 2) zeros += (a[j] == 0);
    *mode = (zeros >= 2) ? 1 : 0;
}

__global__ __launch_bounds__(256) void init_gather(
    const float* __restrict__ data, const void* __restrict__ idxraw,
    const int* __restrict__ mode,
    float* __restrict__ C, int* __restrict__ done)
{
    int t = blockIdx.x * 256 + threadIdx.x;
    if (t < KC * DIM) {
        int k = t >> 6;
        long long src = (*mode) ? ((const long long*)idxraw)[k]
                                : (long long)((const int*)idxraw)[k];
        C[t] = data[(size_t)src * DIM + (t & 63)];
    }
    if (t == 0) *done = 0;
}

__global__ __launch_bounds__(256) void c2_init(
    const float* __restrict__ C, float* __restrict__ c2, int* __restrict__ nanidx)
{
    int k = threadIdx.x;
    float p[DIM];
    #pragma unroll
    for (int d = 0; d < DIM; ++d) p[d] = C[k * DIM + d];
    c2[k] = seq_rowsum_sq64(p);
    __syncthreads();
    if (k == 0) {
        int ni = -1;
        for (int kk = 0; kk < KC; ++kk)
            if (isnan(c2[kk])) { ni = kk; break; }
        *nanidx = ni;
    }
}

// assign: UNCHANGED validated arithmetic.
__global__ __launch_bounds__(256) void assign_k(
    const float* __restrict__ data, const float* __restrict__ C,
    const float* __restrict__ c2, const int* __restrict__ nanidx,
    int* __restrict__ labels, const int* __restrict__ done)
{
    if (*done) return;
    int i = blockIdx.x * 256 + threadIdx.x;
    int ni = *nanidx;
    if (ni >= 0) { labels[i] = ni; return; }

    float p[DIM];
    const float4* r = (const float4*)(data + (size_t)i * DIM);
    #pragma unroll
    for (int j = 0; j < 16; ++j) {
        float4 v = r[j];
        p[4 * j + 0] = v.x; p[4 * j + 1] = v.y;
        p[4 * j + 2] = v.z; p[4 * j + 3] = v.w;
    }
    float xx = seq_rowsum_sq64(p);

    float bestd = INFINITY;
    int best = 0;
    for (int k0 = 0; k0 < KC; k0 += 4) {
        const float* c0 = C + (size_t)k0 * DIM;
        float a0 = 0.f, a1 = 0.f, a2 = 0.f, a3 = 0.f;
        #pragma unroll
        for (int d = 0; d < DIM; ++d) {
            float pd = p[d];
            a0 = fmaf(c0[d], pd, a0);
            a1 = fmaf(c0[DIM + d], pd, a1);
            a2 = fmaf(c0[2 * DIM + d], pd, a2);
            a3 = fmaf(c0[3 * DIM + d], pd, a3);
        }
        float d0 = (xx + c2[k0 + 0]) - 2.f * a0;
        float d1 = (xx + c2[k0 + 1]) - 2.f * a1;
        float d2v = (xx + c2[k0 + 2]) - 2.f * a2;
        float d3 = (xx + c2[k0 + 3]) - 2.f * a3;
        if (d0 < bestd) { bestd = d0; best = k0 + 0; }
        if (d1 < bestd) { bestd = d1; best = k0 + 1; }
        if (d2v < bestd) { bestd = d2v; best = k0 + 2; }
        if (d3 < bestd) { bestd = d3; best = k0 + 3; }
    }
    labels[i] = best;
}

// ---- sort pass A: per-chunk histogram
__global__ __launch_bounds__(256) void hist_k(
    const int* __restrict__ labels, int* __restrict__ hist,
    const int* __restrict__ done)
{
    if (*done) return;
    __shared__ int h[KC];
    int b = blockIdx.x;
    h[threadIdx.x] = 0;
    __syncthreads();
    int base = b * 1024;
    for (int j = threadIdx.x; j < 1024; j += 256)
        atomicAdd(&h[labels[base + j]], 1);
    __syncthreads();
    hist[b * KC + threadIdx.x] = h[threadIdx.x];
}

// ---- sort pass B: column prefix + exclusive scan (integer, order-free)
__global__ __launch_bounds__(256) void prefix_k(
    int* __restrict__ hist, int* __restrict__ seg_start,
    float* __restrict__ counts, const int* __restrict__ done)
{
    if (*done) return;
    int k = threadIdx.x;
    int run = 0;
    #pragma unroll 8
    for (int b = 0; b < 256; ++b) {
        int v = hist[b * KC + k];
        hist[b * KC + k] = run;
        run += v;
    }
    __shared__ int sc[KC];
    sc[k] = run;
    __syncthreads();
    for (int off = 1; off < KC; off <<= 1) {
        int v = (k >= off) ? sc[k - off] : 0;
        __syncthreads();
        sc[k] += v;
        __syncthreads();
    }
    int base = sc[k] - run;
    seg_start[k] = base;
    if (k == 0) seg_start[KC] = N_PTS;
    counts[k] = (float)run;
    #pragma unroll 8
    for (int b = 0; b < 256; ++b)
        hist[b * KC + k] += base;
}

// ---- sort pass C: order-preserving scatter (ascending j per chunk)
__global__ __launch_bounds__(256) void scatter_k(
    const int* __restrict__ labels, const int* __restrict__ hist,
    int* __restrict__ order, const int* __restrict__ done)
{
    if (*done) return;
    __shared__ int lab_s[1024];
    int b = blockIdx.x, k = threadIdx.x;
    int base = b * 1024;
    for (int j = k; j < 1024; j += 256) lab_s[j] = labels[base + j];
    __syncthreads();
    int pos = hist[b * KC + k];
    for (int j = 0; j < 1024; ++j) {
        if (lab_s[j] == k) order[pos++] = base + j;
    }
}

// ---- segment sum, role-separated LDS double-buffer.
// Block = cluster k, 4 waves. Waves 1-3 (192 thr) gather chunk c+1 rows from
// data via order[] into buf[(c+1)&1] (float4, 11 slots/thread max). Wave 0
// ONLY chains chunk c from buf[c&1] (ds_read, unroll-8 for batching).
// One barrier per chunk; parity keeps buffers disjoint.
// Chain: chunks ascending, j ascending -> (label,i)-ascending adds. EXACT.
__global__ __launch_bounds__(256) void sum_staged2(
    const float* __restrict__ data, const int* __restrict__ order,
    const int* __restrict__ seg_start, float* __restrict__ sums,
    const int* __restrict__ done)
{
    if (*done) return;
    __shared__ float buf[2][128][DIM];      // 64 KB
    int k = blockIdx.x;
    int t = threadIdx.x;
    int beg = seg_start[k], end = seg_start[k + 1];
    int n = end - beg;
    int nchunk = (n + 127) >> 7;
    bool stager = (t >= 64);
    int st = t - 64;                        // 0..191 for stagers

#define STAGE(c, which)                                                       \
    {                                                                         \
        int _base = beg + ((c) << 7);                                         \
        int _m = n - ((c) << 7); if (_m > 128) _m = 128;                      \
        int _slots = _m << 4;               /* rows * 16 float4-slots */      \
        _Pragma("unroll")                                                     \
        for (int i2 = 0; i2 < 11; ++i2) {                                     \
            int slot = st + i2 * 192;                                         \
            if (slot < _slots) {                                              \
                int row = slot >> 4, q = slot & 15;                           \
                int src = order[_base + row];                                 \
                float4 v = ((const float4*)(data + (size_t)src * DIM))[q];    \
                ((float4*)&buf[which][row][0])[q] = v;                        \
            }                                                                 \
        }                                                                     \
    }

    if (stager && nchunk > 0) STAGE(0, 0);
    __syncthreads();

    float s = 0.f;
    int d = t & 63;
    for (int c = 0; c < nchunk; ++c) {
        if (stager) {
            if (c + 1 < nchunk) STAGE(c + 1, (c + 1) & 1);
        } else if (t < 64) {
            int m = n - (c << 7); if (m > 128) m = 128;
            int cur = c & 1;
            #pragma unroll 8
            for (int j = 0; j < m; ++j)
                s = s + buf[cur][j][d];     // sequential chain, lane = dim
        }
        __syncthreads();
    }
#undef STAGE
    if (t < 64) sums[k * DIM + d] = s;
}

// fallback segment-sum (validated R11) when ws has no room for sort buffers
__global__ __launch_bounds__(64) void accum_scan(
    const float* __restrict__ data, const int* __restrict__ labels,
    float* __restrict__ sums, float* __restrict__ counts,
    const int* __restrict__ done)
{
    if (*done) return;
    int k = blockIdx.x;
    int d = threadIdx.x;
    __shared__ int lab_s[1024];
    float s = 0.f;
    int cnt = 0;
    for (int base = 0; base < N_PTS; base += 1024) {
        for (int j = d; j < 1024; j += 64) lab_s[j] = labels[base + j];
        __syncthreads();
        #pragma unroll 8
        for (int j = 0; j < 1024; ++j) {
            if (lab_s[j] == k) { s = s + data[(size_t)(base + j) * DIM + d]; ++cnt; }
        }
        __syncthreads();
    }
    sums[k * DIM + d] = s;
    if (d == 0) counts[k] = (float)cnt;
}

// ---- update + c2 fused (validated)
__global__ __launch_bounds__(256) void update_c2_k(
    float* __restrict__ C, const float* __restrict__ sums,
    const float* __restrict__ counts, float* __restrict__ c2,
    int* __restrict__ nanidx, int* __restrict__ done)
{
    if (*done) return;
    __shared__ double red[256];
    int k = threadIdx.x;

    float cnt = counts[k];
    float nc[DIM];
    double local = 0.0;
    #pragma unroll
    for (int d = 0; d < DIM; ++d) {
        float v = sums[k * DIM + d] / cnt;
        nc[d] = v;
        float old = C[k * DIM + d];
        double diff = (double)v - (double)old;
        local = fma(diff, diff, local);
        C[k * DIM + d] = v;
    }
    c2[k] = seq_rowsum_sq64(nc);

    red[k] = local;
    __syncthreads();
    if (k == 0) {
        int ni = -1;
        for (int kk = 0; kk < KC; ++kk)
            if (isnan(c2[kk])) { ni = kk; break; }
        *nanidx = ni;
    }
    for (int s = 128; s > 0; s >>= 1) {
        if (k < s) red[k] += red[k + s];
        __syncthreads();
    }
    if (k == 0 && red[0] < 1e-8) *done = 1;    // (1e-4)^2, NaN stays not-done
}

extern "C" void kernel_launch(void* const* d_in, const int* in_sizes, int n_in,
                              void* d_out, int out_size, void* d_ws, size_t ws_size,
                              hipStream_t stream)
{
    const float* data = (const float*)d_in[0];
    const void*  idx  = d_in[1];
    int* labels = (int*)d_out;

    float* C      = (float*)d_ws;               // 16384 f
    float* sums   = C + KC * DIM;               // 16384 f
    float* counts = sums + KC * DIM;            // 256 f
    float* c2     = counts + KC;                // 256 f
    int*   done      = (int*)(c2 + KC);
    int*   mode      = done + 1;
    int*   nanidx    = done + 2;
    int*   seg_start = done + 4;                // 257 ints
    int*   hist      = seg_start + 260;         // 65536 ints
    int*   order     = hist + KC * 256;         // 262144 ints
    size_t need_sort = (size_t)((char*)(order + N_PTS) - (char*)d_ws);
    bool fast = ws_size >= need_sort;           // ~1.4 MB

    detect_idx<<<1, 1, 0, stream>>>((const int*)idx, mode);
    init_gather<<<64, 256, 0, stream>>>(data, idx, mode, C, done);
    c2_init<<<1, 256, 0, stream>>>(C, c2, nanidx);

    for (int it = 0; it < MAX_ITERS; ++it) {
        assign_k<<<N_PTS / 256, 256, 0, stream>>>(data, C, c2, nanidx, labels, done);
        if (fast) {
            hist_k<<<256, 256, 0, stream>>>(labels, hist, done);
            prefix_k<<<1, 256, 0, stream>>>(hist, seg_start, counts, done);
            scatter_k<<<256, 256, 0, stream>>>(labels, hist, order, done);
            sum_staged2<<<KC, 256, 0, stream>>>(data, order, seg_start, sums, done);
        } else {
            accum_scan<<<KC, 64, 0, stream>>>(data, labels, sums, counts, done);
        }
        update_c2_k<<<1, 256, 0, stream>>>(C, sums, counts, c2, nanidx, done);
    }
}

// Round 20
// 3485.669 us; speedup vs baseline: 1.2508x; 1.2508x over previous
//
#include <hip/hip_runtime.h>
#include <math.h>

#define N_PTS 262144
#define KC 256
#define DIM 64
#define MAX_ITERS 10

// ===========================================================================
// Bit-exact XLA:CPU f32 arithmetic (validated R11-R19 — DO NOT ALTER):
//   x2/c2: rounded squares (fmaf(v,v,0)) + strict sequential f32 add chain
//   dot:   ascending-k FMA chain;  d2 = (x2 + c2) - 2*dot
//   argmin: strict-< first-min, first-NaN override
//   segment_sum: per (k,d), i-ascending sequential plain f32 adds
//   update: f32 sums/counts division (0/0 -> NaN)
// R20: diagnosis — the sum dispatch is TAIL-DOMINATED by the largest cluster
// (occupancy 0.58%): one block runs ~60 chunks while the rest idle, and R19's
// stagers serialized order[]->data dependent random gathers (~12-38K cyc per
// chunk). Fix: gather to contiguous sdata first (full-grid parallel, R14-
// validated), then 8-wave blocks: wave 0 chains from LDS only, waves 1-7
// stage coalesced float4 from sdata (5 independent loads/thread) -> stage is
// BW-bound, chain ~6cyc/elem, tail ~= n_max*(4-8cyc) ~= 20-85us.
// ===========================================================================

__device__ __forceinline__ float seq_rowsum_sq64(const float* p)
{
    float s = fmaf(p[0], p[0], 0.f);
    #pragma unroll
    for (int d = 1; d < DIM; ++d) s = s + fmaf(p[d], p[d], 0.f);
    return s;
}

__global__ void detect_idx(const int* __restrict__ a, int* __restrict__ mode)
{
    int zeros = 0;
    for (int j = 1; j < 256; j += 2) zeros += (a[j] == 0);
    *mode = (zeros >= 2) ? 1 : 0;
}

__global__ __launch_bounds__(256) void init_gather(
    const float* __restrict__ data, const void* __restrict__ idxraw,
    const int* __restrict__ mode,
    float* __restrict__ C, int* __restrict__ done)
{
    int t = blockIdx.x * 256 + threadIdx.x;
    if (t < KC * DIM) {
        int k = t >> 6;
        long long src = (*mode) ? ((const long long*)idxraw)[k]
                                : (long long)((const int*)idxraw)[k];
        C[t] = data[(size_t)src * DIM + (t & 63)];
    }
    if (t == 0) *done = 0;
}

__global__ __launch_bounds__(256) void c2_init(
    const float* __restrict__ C, float* __restrict__ c2, int* __restrict__ nanidx)
{
    int k = threadIdx.x;
    float p[DIM];
    #pragma unroll
    for (int d = 0; d < DIM; ++d) p[d] = C[k * DIM + d];
    c2[k] = seq_rowsum_sq64(p);
    __syncthreads();
    if (k == 0) {
        int ni = -1;
        for (int kk = 0; kk < KC; ++kk)
            if (isnan(c2[kk])) { ni = kk; break; }
        *nanidx = ni;
    }
}

// assign: UNCHANGED validated arithmetic.
__global__ __launch_bounds__(256) void assign_k(
    const float* __restrict__ data, const float* __restrict__ C,
    const float* __restrict__ c2, const int* __restrict__ nanidx,
    int* __restrict__ labels, const int* __restrict__ done)
{
    if (*done) return;
    int i = blockIdx.x * 256 + threadIdx.x;
    int ni = *nanidx;
    if (ni >= 0) { labels[i] = ni; return; }

    float p[DIM];
    const float4* r = (const float4*)(data + (size_t)i * DIM);
    #pragma unroll
    for (int j = 0; j < 16; ++j) {
        float4 v = r[j];
        p[4 * j + 0] = v.x; p[4 * j + 1] = v.y;
        p[4 * j + 2] = v.z; p[4 * j + 3] = v.w;
    }
    float xx = seq_rowsum_sq64(p);

    float bestd = INFINITY;
    int best = 0;
    for (int k0 = 0; k0 < KC; k0 += 4) {
        const float* c0 = C + (size_t)k0 * DIM;
        float a0 = 0.f, a1 = 0.f, a2 = 0.f, a3 = 0.f;
        #pragma unroll
        for (int d = 0; d < DIM; ++d) {
            float pd = p[d];
            a0 = fmaf(c0[d], pd, a0);
            a1 = fmaf(c0[DIM + d], pd, a1);
            a2 = fmaf(c0[2 * DIM + d], pd, a2);
            a3 = fmaf(c0[3 * DIM + d], pd, a3);
        }
        float d0 = (xx + c2[k0 + 0]) - 2.f * a0;
        float d1 = (xx + c2[k0 + 1]) - 2.f * a1;
        float d2v = (xx + c2[k0 + 2]) - 2.f * a2;
        float d3 = (xx + c2[k0 + 3]) - 2.f * a3;
        if (d0 < bestd) { bestd = d0; best = k0 + 0; }
        if (d1 < bestd) { bestd = d1; best = k0 + 1; }
        if (d2v < bestd) { bestd = d2v; best = k0 + 2; }
        if (d3 < bestd) { bestd = d3; best = k0 + 3; }
    }
    labels[i] = best;
}

// ---- sort pass A: per-chunk histogram
__global__ __launch_bounds__(256) void hist_k(
    const int* __restrict__ labels, int* __restrict__ hist,
    const int* __restrict__ done)
{
    if (*done) return;
    __shared__ int h[KC];
    int b = blockIdx.x;
    h[threadIdx.x] = 0;
    __syncthreads();
    int base = b * 1024;
    for (int j = threadIdx.x; j < 1024; j += 256)
        atomicAdd(&h[labels[base + j]], 1);
    __syncthreads();
    hist[b * KC + threadIdx.x] = h[threadIdx.x];
}

// ---- sort pass B: column prefix + exclusive scan (integer, order-free)
__global__ __launch_bounds__(256) void prefix_k(
    int* __restrict__ hist, int* __restrict__ seg_start,
    float* __restrict__ counts, const int* __restrict__ done)
{
    if (*done) return;
    int k = threadIdx.x;
    int run = 0;
    #pragma unroll 8
    for (int b = 0; b < 256; ++b) {
        int v = hist[b * KC + k];
        hist[b * KC + k] = run;
        run += v;
    }
    __shared__ int sc[KC];
    sc[k] = run;
    __syncthreads();
    for (int off = 1; off < KC; off <<= 1) {
        int v = (k >= off) ? sc[k - off] : 0;
        __syncthreads();
        sc[k] += v;
        __syncthreads();
    }
    int base = sc[k] - run;
    seg_start[k] = base;
    if (k == 0) seg_start[KC] = N_PTS;
    counts[k] = (float)run;
    #pragma unroll 8
    for (int b = 0; b < 256; ++b)
        hist[b * KC + k] += base;
}

// ---- sort pass C: order-preserving scatter (ascending j per chunk)
__global__ __launch_bounds__(256) void scatter_k(
    const int* __restrict__ labels, const int* __restrict__ hist,
    int* __restrict__ order, const int* __restrict__ done)
{
    if (*done) return;
    __shared__ int lab_s[1024];
    int b = blockIdx.x, k = threadIdx.x;
    int base = b * 1024;
    for (int j = k; j < 1024; j += 256) lab_s[j] = labels[base + j];
    __syncthreads();
    int pos = hist[b * KC + k];
    for (int j = 0; j < 1024; ++j) {
        if (lab_s[j] == k) order[pos++] = base + j;
    }
}

// ---- parallel row gather into sorted contiguous sdata (value-exact, R14)
__global__ __launch_bounds__(256) void gather_sorted(
    const float* __restrict__ data, const int* __restrict__ order,
    float* __restrict__ sdata, const int* __restrict__ done)
{
    if (*done) return;
    int gid = blockIdx.x * 256 + threadIdx.x;       // N_PTS*16 total
    int p = gid >> 4, q = gid & 15;
    int src = order[p];
    const float4* s4 = (const float4*)(data + (size_t)src * DIM);
    ((float4*)(sdata + (size_t)p * DIM))[q] = s4[q];
}

// ---- segment sum: 8-wave role-separated LDS double-buffer over CONTIGUOUS
// sdata. Wave 0 = chain (LDS reads only); waves 1-7 (448 thr) = stagers,
// 5 independent coalesced float4 loads each per 128-row chunk (32KB).
// Barrier per chunk; parity keeps buffers disjoint. Chain: chunks ascending,
// j ascending = (label,i) ascending. EXACT.
__global__ __launch_bounds__(512) void sum_staged3(
    const float* __restrict__ sdata, const int* __restrict__ seg_start,
    float* __restrict__ sums, const int* __restrict__ done)
{
    if (*done) return;
    __shared__ float buf[2][128][DIM];      // 64 KB
    int k = blockIdx.x;
    int t = threadIdx.x;
    int beg = seg_start[k], end = seg_start[k + 1];
    int n = end - beg;
    int nchunk = (n + 127) >> 7;
    bool stager = (t >= 64);
    int st = t - 64;                        // 0..447

#define STAGE(c, which)                                                       \
    {                                                                         \
        int _m = n - ((c) << 7); if (_m > 128) _m = 128;                      \
        int _slots = _m << 4;               /* rows * 16 float4-slots */      \
        const float4* _src = (const float4*)(sdata + ((size_t)(beg + ((c) << 7)) * DIM)); \
        _Pragma("unroll")                                                     \
        for (int i2 = 0; i2 < 5; ++i2) {                                      \
            int slot = st + i2 * 448;                                         \
            if (slot < _slots)                                                \
                ((float4*)&buf[which][0][0])[slot] = _src[slot];              \
        }                                                                     \
    }

    if (stager && nchunk > 0) STAGE(0, 0);
    __syncthreads();

    float s = 0.f;
    int d = t & 63;
    for (int c = 0; c < nchunk; ++c) {
        if (stager) {
            if (c + 1 < nchunk) STAGE(c + 1, (c + 1) & 1);
        } else {
            int m = n - (c << 7); if (m > 128) m = 128;
            int cur = c & 1;
            #pragma unroll 8
            for (int j = 0; j < m; ++j)
                s = s + buf[cur][j][d];     // sequential chain, lane = dim
        }
        __syncthreads();
    }
#undef STAGE
    if (t < 64) sums[k * DIM + d] = s;
}

// fallback segment-sum (validated R11) when ws has no room for sort buffers
__global__ __launch_bounds__(64) void accum_scan(
    const float* __restrict__ data, const int* __restrict__ labels,
    float* __restrict__ sums, float* __restrict__ counts,
    const int* __restrict__ done)
{
    if (*done) return;
    int k = blockIdx.x;
    int d = threadIdx.x;
    __shared__ int lab_s[1024];
    float s = 0.f;
    int cnt = 0;
    for (int base = 0; base < N_PTS; base += 1024) {
        for (int j = d; j < 1024; j += 64) lab_s[j] = labels[base + j];
        __syncthreads();
        #pragma unroll 8
        for (int j = 0; j < 1024; ++j) {
            if (lab_s[j] == k) { s = s + data[(size_t)(base + j) * DIM + d]; ++cnt; }
        }
        __syncthreads();
    }
    sums[k * DIM + d] = s;
    if (d == 0) counts[k] = (float)cnt;
}

// ---- update + c2 fused (validated)
__global__ __launch_bounds__(256) void update_c2_k(
    float* __restrict__ C, const float* __restrict__ sums,
    const float* __restrict__ counts, float* __restrict__ c2,
    int* __restrict__ nanidx, int* __restrict__ done)
{
    if (*done) return;
    __shared__ double red[256];
    int k = threadIdx.x;

    float cnt = counts[k];
    float nc[DIM];
    double local = 0.0;
    #pragma unroll
    for (int d = 0; d < DIM; ++d) {
        float v = sums[k * DIM + d] / cnt;
        nc[d] = v;
        float old = C[k * DIM + d];
        double diff = (double)v - (double)old;
        local = fma(diff, diff, local);
        C[k * DIM + d] = v;
    }
    c2[k] = seq_rowsum_sq64(nc);

    red[k] = local;
    __syncthreads();
    if (k == 0) {
        int ni = -1;
        for (int kk = 0; kk < KC; ++kk)
            if (isnan(c2[kk])) { ni = kk; break; }
        *nanidx = ni;
    }
    for (int s = 128; s > 0; s >>= 1) {
        if (k < s) red[k] += red[k + s];
        __syncthreads();
    }
    if (k == 0 && red[0] < 1e-8) *done = 1;    // (1e-4)^2, NaN stays not-done
}

extern "C" void kernel_launch(void* const* d_in, const int* in_sizes, int n_in,
                              void* d_out, int out_size, void* d_ws, size_t ws_size,
                              hipStream_t stream)
{
    const float* data = (const float*)d_in[0];
    const void*  idx  = d_in[1];
    int* labels = (int*)d_out;

    float* C      = (float*)d_ws;               // 16384 f
    float* sums   = C + KC * DIM;               // 16384 f
    float* counts = sums + KC * DIM;            // 256 f
    float* c2     = counts + KC;                // 256 f
    int*   done      = (int*)(c2 + KC);
    int*   mode      = done + 1;
    int*   nanidx    = done + 2;
    int*   seg_start = done + 4;                // 257 ints
    int*   hist      = seg_start + 260;         // 65536 ints
    int*   order     = hist + KC * 256;         // 262144 ints
    float* sdata     = (float*)(order + N_PTS); // 16777216 f = 64 MB
    size_t need_sort   = (size_t)((char*)sdata - (char*)d_ws);
    size_t need_gather = need_sort + (size_t)N_PTS * DIM * sizeof(float);
    bool fast   = ws_size >= need_sort;
    bool faster = ws_size >= need_gather;

    detect_idx<<<1, 1, 0, stream>>>((const int*)idx, mode);
    init_gather<<<64, 256, 0, stream>>>(data, idx, mode, C, done);
    c2_init<<<1, 256, 0, stream>>>(C, c2, nanidx);

    for (int it = 0; it < MAX_ITERS; ++it) {
        assign_k<<<N_PTS / 256, 256, 0, stream>>>(data, C, c2, nanidx, labels, done);
        if (fast && faster) {
            hist_k<<<256, 256, 0, stream>>>(labels, hist, done);
            prefix_k<<<1, 256, 0, stream>>>(hist, seg_start, counts, done);
            scatter_k<<<256, 256, 0, stream>>>(labels, hist, order, done);
            gather_sorted<<<N_PTS * 16 / 256, 256, 0, stream>>>(data, order, sdata, done);
            sum_staged3<<<KC, 512, 0, stream>>>(sdata, seg_start, sums, done);
        } else {
            accum_scan<<<KC, 64, 0, stream>>>(data, labels, sums, counts, done);
        }
        update_c2_k<<<1, 256, 0, stream>>>(C, sums, counts, c2, nanidx, done);
    }
}

// Round 21
// 3340.226 us; speedup vs baseline: 1.3052x; 1.0435x over previous
//
#include <hip/hip_runtime.h>
#include <math.h>

#define N_PTS 262144
#define KC 256
#define DIM 64
#define MAX_ITERS 10

// ===========================================================================
// Bit-exact XLA:CPU f32 arithmetic (validated R11-R20 — DO NOT ALTER):
//   x2/c2: rounded squares (fmaf(v,v,0)) + strict sequential f32 add chain
//   dot:   ascending-k FMA chain;  d2 = (x2 + c2) - 2*dot
//   argmin: strict-< first-min, first-NaN override
//   segment_sum: per (k,d), i-ascending sequential plain f32 adds
//   update: f32 sums/counts division (0/0 -> NaN)
// R21: tail cluster is ~40-50K points (calibrated from R12/R15/R20 timings)
// -> serial add chain floor ~80-100us/iter. T14 async-STAGE split: stagers
// keep next chunk in REGISTERS (order prefetched a chunk early -> no dep
// chain in-phase), ds_write just before barrier; chain wave = ds_read+add
// only. gather_sorted/sdata eliminated (stage reads data directly).
// ===========================================================================

__device__ __forceinline__ float seq_rowsum_sq64(const float* p)
{
    float s = fmaf(p[0], p[0], 0.f);
    #pragma unroll
    for (int d = 1; d < DIM; ++d) s = s + fmaf(p[d], p[d], 0.f);
    return s;
}

__global__ void detect_idx(const int* __restrict__ a, int* __restrict__ mode)
{
    int zeros = 0;
    for (int j = 1; j < 256; j += 2) zeros += (a[j] == 0);
    *mode = (zeros >= 2) ? 1 : 0;
}

__global__ __launch_bounds__(256) void init_gather(
    const float* __restrict__ data, const void* __restrict__ idxraw,
    const int* __restrict__ mode,
    float* __restrict__ C, int* __restrict__ done)
{
    int t = blockIdx.x * 256 + threadIdx.x;
    if (t < KC * DIM) {
        int k = t >> 6;
        long long src = (*mode) ? ((const long long*)idxraw)[k]
                                : (long long)((const int*)idxraw)[k];
        C[t] = data[(size_t)src * DIM + (t & 63)];
    }
    if (t == 0) *done = 0;
}

__global__ __launch_bounds__(256) void c2_init(
    const float* __restrict__ C, float* __restrict__ c2, int* __restrict__ nanidx)
{
    int k = threadIdx.x;
    float p[DIM];
    #pragma unroll
    for (int d = 0; d < DIM; ++d) p[d] = C[k * DIM + d];
    c2[k] = seq_rowsum_sq64(p);
    __syncthreads();
    if (k == 0) {
        int ni = -1;
        for (int kk = 0; kk < KC; ++kk)
            if (isnan(c2[kk])) { ni = kk; break; }
        *nanidx = ni;
    }
}

// assign: UNCHANGED validated arithmetic.
__global__ __launch_bounds__(256) void assign_k(
    const float* __restrict__ data, const float* __restrict__ C,
    const float* __restrict__ c2, const int* __restrict__ nanidx,
    int* __restrict__ labels, const int* __restrict__ done)
{
    if (*done) return;
    int i = blockIdx.x * 256 + threadIdx.x;
    int ni = *nanidx;
    if (ni >= 0) { labels[i] = ni; return; }

    float p[DIM];
    const float4* r = (const float4*)(data + (size_t)i * DIM);
    #pragma unroll
    for (int j = 0; j < 16; ++j) {
        float4 v = r[j];
        p[4 * j + 0] = v.x; p[4 * j + 1] = v.y;
        p[4 * j + 2] = v.z; p[4 * j + 3] = v.w;
    }
    float xx = seq_rowsum_sq64(p);

    float bestd = INFINITY;
    int best = 0;
    for (int k0 = 0; k0 < KC; k0 += 4) {
        const float* c0 = C + (size_t)k0 * DIM;
        float a0 = 0.f, a1 = 0.f, a2 = 0.f, a3 = 0.f;
        #pragma unroll
        for (int d = 0; d < DIM; ++d) {
            float pd = p[d];
            a0 = fmaf(c0[d], pd, a0);
            a1 = fmaf(c0[DIM + d], pd, a1);
            a2 = fmaf(c0[2 * DIM + d], pd, a2);
            a3 = fmaf(c0[3 * DIM + d], pd, a3);
        }
        float d0 = (xx + c2[k0 + 0]) - 2.f * a0;
        float d1 = (xx + c2[k0 + 1]) - 2.f * a1;
        float d2v = (xx + c2[k0 + 2]) - 2.f * a2;
        float d3 = (xx + c2[k0 + 3]) - 2.f * a3;
        if (d0 < bestd) { bestd = d0; best = k0 + 0; }
        if (d1 < bestd) { bestd = d1; best = k0 + 1; }
        if (d2v < bestd) { bestd = d2v; best = k0 + 2; }
        if (d3 < bestd) { bestd = d3; best = k0 + 3; }
    }
    labels[i] = best;
}

// ---- sort pass A: per-chunk histogram
__global__ __launch_bounds__(256) void hist_k(
    const int* __restrict__ labels, int* __restrict__ hist,
    const int* __restrict__ done)
{
    if (*done) return;
    __shared__ int h[KC];
    int b = blockIdx.x;
    h[threadIdx.x] = 0;
    __syncthreads();
    int base = b * 1024;
    for (int j = threadIdx.x; j < 1024; j += 256)
        atomicAdd(&h[labels[base + j]], 1);
    __syncthreads();
    hist[b * KC + threadIdx.x] = h[threadIdx.x];
}

// ---- sort pass B: column prefix + exclusive scan (integer, order-free)
__global__ __launch_bounds__(256) void prefix_k(
    int* __restrict__ hist, int* __restrict__ seg_start,
    float* __restrict__ counts, const int* __restrict__ done)
{
    if (*done) return;
    int k = threadIdx.x;
    int run = 0;
    #pragma unroll 8
    for (int b = 0; b < 256; ++b) {
        int v = hist[b * KC + k];
        hist[b * KC + k] = run;
        run += v;
    }
    __shared__ int sc[KC];
    sc[k] = run;
    __syncthreads();
    for (int off = 1; off < KC; off <<= 1) {
        int v = (k >= off) ? sc[k - off] : 0;
        __syncthreads();
        sc[k] += v;
        __syncthreads();
    }
    int base = sc[k] - run;
    seg_start[k] = base;
    if (k == 0) seg_start[KC] = N_PTS;
    counts[k] = (float)run;
    #pragma unroll 8
    for (int b = 0; b < 256; ++b)
        hist[b * KC + k] += base;
}

// ---- sort pass C: order-preserving scatter (ascending j per chunk)
__global__ __launch_bounds__(256) void scatter_k(
    const int* __restrict__ labels, const int* __restrict__ hist,
    int* __restrict__ order, const int* __restrict__ done)
{
    if (*done) return;
    __shared__ int lab_s[1024];
    int b = blockIdx.x, k = threadIdx.x;
    int base = b * 1024;
    for (int j = k; j < 1024; j += 256) lab_s[j] = labels[base + j];
    __syncthreads();
    int pos = hist[b * KC + k];
    for (int j = 0; j < 1024; ++j) {
        if (lab_s[j] == k) order[pos++] = base + j;
    }
}

// ---- segment sum, T14 async-STAGE pipeline. Block = cluster, 512 threads.
// Wave 0 chains chunk c from LDS only. Waves 1-7 (448 thr x 5 slots): order
// for chunk c+1 was prefetched LAST chunk -> data loads issue immediately
// (branch-free clamped addresses, predicated writes), land under the chain's
// compute, ds_write before barrier. Chain order: chunks asc, j asc. EXACT.
__global__ __launch_bounds__(512) void sum_pipe(
    const float* __restrict__ data, const int* __restrict__ order,
    const int* __restrict__ seg_start, float* __restrict__ sums,
    const int* __restrict__ done)
{
    if (*done) return;
    __shared__ float buf[2][128][DIM];      // 64 KB
    int k = blockIdx.x;
    int t = threadIdx.x;
    int beg = seg_start[k], end = seg_start[k + 1];
    int n = end - beg;
    int nchunk = (n + 127) >> 7;
    bool stager = (t >= 64);
    int st = t - 64;                        // 0..447

    int row[5], q[5], src[5];
    #pragma unroll
    for (int i = 0; i < 5; ++i) {
        int sl = st + i * 448;              // 0..2239 (slots used: < m*16)
        row[i] = sl >> 4; q[i] = sl & 15;
    }
#define RC(r, m) ((r) < (m) ? (r) : (m) - 1)

    // prologue: stage chunk 0 synchronously; prefetch order for chunk 1
    if (stager && nchunk > 0) {
        int m0 = n < 128 ? n : 128;
        int s0[5];
        #pragma unroll
        for (int i = 0; i < 5; ++i) s0[i] = order[beg + RC(row[i], m0)];
        float4 v[5];
        #pragma unroll
        for (int i = 0; i < 5; ++i)
            v[i] = ((const float4*)(data + (size_t)s0[i] * DIM))[q[i]];
        #pragma unroll
        for (int i = 0; i < 5; ++i)
            if (row[i] < m0)
                ((float4*)&buf[0][0][0])[st + i * 448] = v[i];
        if (nchunk > 1) {
            int m1 = n - 128; if (m1 > 128) m1 = 128;
            #pragma unroll
            for (int i = 0; i < 5; ++i)
                src[i] = order[beg + 128 + RC(row[i], m1)];
        }
    }
    __syncthreads();

    float s = 0.f;
    for (int c = 0; c < nchunk; ++c) {
        if (stager) {
            if (c + 1 < nchunk) {
                int m1 = n - ((c + 1) << 7); if (m1 > 128) m1 = 128;
                float4 v[5];
                #pragma unroll
                for (int i = 0; i < 5; ++i)
                    v[i] = ((const float4*)(data + (size_t)src[i] * DIM))[q[i]];
                if (c + 2 < nchunk) {       // prefetch order for c+2
                    int b2 = beg + ((c + 2) << 7);
                    int m2 = n - ((c + 2) << 7); if (m2 > 128) m2 = 128;
                    #pragma unroll
                    for (int i = 0; i < 5; ++i)
                        src[i] = order[b2 + RC(row[i], m2)];
                }
                int nxt = (c + 1) & 1;
                #pragma unroll
                for (int i = 0; i < 5; ++i)
                    if (row[i] < m1)
                        ((float4*)&buf[nxt][0][0])[st + i * 448] = v[i];
            }
        } else {
            int m = n - (c << 7); if (m > 128) m = 128;
            int cur = c & 1;
            #pragma unroll 16
            for (int j = 0; j < m; ++j)
                s = s + buf[cur][j][t];     // sequential chain, lane = dim
        }
        __syncthreads();
    }
#undef RC
    if (t < 64) sums[k * DIM + t] = s;
}

// fallback segment-sum (validated R11) when ws has no room for sort buffers
__global__ __launch_bounds__(64) void accum_scan(
    const float* __restrict__ data, const int* __restrict__ labels,
    float* __restrict__ sums, float* __restrict__ counts,
    const int* __restrict__ done)
{
    if (*done) return;
    int k = blockIdx.x;
    int d = threadIdx.x;
    __shared__ int lab_s[1024];
    float s = 0.f;
    int cnt = 0;
    for (int base = 0; base < N_PTS; base += 1024) {
        for (int j = d; j < 1024; j += 64) lab_s[j] = labels[base + j];
        __syncthreads();
        #pragma unroll 8
        for (int j = 0; j < 1024; ++j) {
            if (lab_s[j] == k) { s = s + data[(size_t)(base + j) * DIM + d]; ++cnt; }
        }
        __syncthreads();
    }
    sums[k * DIM + d] = s;
    if (d == 0) counts[k] = (float)cnt;
}

// ---- update + c2 fused (validated)
__global__ __launch_bounds__(256) void update_c2_k(
    float* __restrict__ C, const float* __restrict__ sums,
    const float* __restrict__ counts, float* __restrict__ c2,
    int* __restrict__ nanidx, int* __restrict__ done)
{
    if (*done) return;
    __shared__ double red[256];
    int k = threadIdx.x;

    float cnt = counts[k];
    float nc[DIM];
    double local = 0.0;
    #pragma unroll
    for (int d = 0; d < DIM; ++d) {
        float v = sums[k * DIM + d] / cnt;
        nc[d] = v;
        float old = C[k * DIM + d];
        double diff = (double)v - (double)old;
        local = fma(diff, diff, local);
        C[k * DIM + d] = v;
    }
    c2[k] = seq_rowsum_sq64(nc);

    red[k] = local;
    __syncthreads();
    if (k == 0) {
        int ni = -1;
        for (int kk = 0; kk < KC; ++kk)
            if (isnan(c2[kk])) { ni = kk; break; }
        *nanidx = ni;
    }
    for (int s = 128; s > 0; s >>= 1) {
        if (k < s) red[k] += red[k + s];
        __syncthreads();
    }
    if (k == 0 && red[0] < 1e-8) *done = 1;    // (1e-4)^2, NaN stays not-done
}

extern "C" void kernel_launch(void* const* d_in, const int* in_sizes, int n_in,
                              void* d_out, int out_size, void* d_ws, size_t ws_size,
                              hipStream_t stream)
{
    const float* data = (const float*)d_in[0];
    const void*  idx  = d_in[1];
    int* labels = (int*)d_out;

    float* C      = (float*)d_ws;               // 16384 f
    float* sums   = C + KC * DIM;               // 16384 f
    float* counts = sums + KC * DIM;            // 256 f
    float* c2     = counts + KC;                // 256 f
    int*   done      = (int*)(c2 + KC);
    int*   mode      = done + 1;
    int*   nanidx    = done + 2;
    int*   seg_start = done + 4;                // 257 ints
    int*   hist      = seg_start + 260;         // 65536 ints
    int*   order     = hist + KC * 256;         // 262144 ints
    size_t need_sort = (size_t)((char*)(order + N_PTS) - (char*)d_ws);
    bool fast = ws_size >= need_sort;           // ~1.4 MB

    detect_idx<<<1, 1, 0, stream>>>((const int*)idx, mode);
    init_gather<<<64, 256, 0, stream>>>(data, idx, mode, C, done);
    c2_init<<<1, 256, 0, stream>>>(C, c2, nanidx);

    for (int it = 0; it < MAX_ITERS; ++it) {
        assign_k<<<N_PTS / 256, 256, 0, stream>>>(data, C, c2, nanidx, labels, done);
        if (fast) {
            hist_k<<<256, 256, 0, stream>>>(labels, hist, done);
            prefix_k<<<1, 256, 0, stream>>>(hist, seg_start, counts, done);
            scatter_k<<<256, 256, 0, stream>>>(labels, hist, order, done);
            sum_pipe<<<KC, 512, 0, stream>>>(data, order, seg_start, sums, done);
        } else {
            accum_scan<<<KC, 64, 0, stream>>>(data, labels, sums, counts, done);
        }
        update_c2_k<<<1, 256, 0, stream>>>(C, sums, counts, c2, nanidx, done);
    }
}